// Round 4
// baseline (15.943 us; speedup 1.0000x reference)
//
#include <hip/hip_runtime.h>

#define NRES 23
#define NA37 37
#define NSC  34
#define DIM  128
#define RAD2 64.0f

// K1: per-residue precompute. grid = BL blocks x 128 threads.
//  S[bl,d]   = sum_a vm*(re[bl,d] + vm*ae[a+3,d])   (atom-summed sc_emb)
//  meta4[bl] = {ca_x, ca_y, ca_z, |ca|^2} (mask-scaled)
//  rtm[bl]   = {mask, restype}
__global__ __launch_bounds__(128) void k_pre(
        const float* __restrict__ aa,   // (BL,23)
        const float* __restrict__ re,   // (BL,128)
        const float* __restrict__ bb,   // (BL,4,3)
        const float* __restrict__ mask, // (BL,)
        const float* __restrict__ tbl,  // (23,37)
        const float* __restrict__ ae,   // (37,128)
        float* __restrict__ S,          // (BL,128)
        float4* __restrict__ meta4,     // (BL,)
        float2* __restrict__ rtm)       // (BL,)
{
    int bi = blockIdx.x;
    int d  = threadIdx.x;

    // argmax over aa_pred[bi, 0:20]; cols 20..22 are -1e9 in the reference
    // and can never win against finite normals. First-max tie-break.
    const float* aarow = aa + (size_t)bi * NRES;
    int rt = 0; float best = aarow[0];
#pragma unroll
    for (int k = 1; k < 20; ++k) {
        float v = aarow[k];
        if (v > best) { best = v; rt = k; }
    }

    float m = mask[bi];
    const float* trow = tbl + rt * NA37 + 3;
    float red = re[(size_t)bi * DIM + d];
    float s = 0.f;
#pragma unroll
    for (int a = 0; a < NSC; ++a) {
        float vm = trow[a] * m;
        s += vm * (red + vm * ae[(a + 3) * DIM + d]);
    }
    S[(size_t)bi * DIM + d] = s;

    if (d == 0) {
        const float* bbr = bb + (size_t)bi * 12 + 3;  // atom 1 = CA
        float x = bbr[0] * m, y = bbr[1] * m, z = bbr[2] * m;
        meta4[bi] = make_float4(x, y, z, x * x + y * y + z * z);
        rtm[bi]   = make_float2(m, (float)rt);
    }
}

// K2: block (b,i), 128 threads (one per dim d).
//  phase 1: coalesced float4/float2 stage of batch-b meta into LDS
//  phase 2: thread t tests d2(i,t) -> __ballot -> 128-bit neighbor mask
//  phase 3: r = sum over set bits of S[j,d]  (~2-6 L2-hot loads)
//  phase 4: out[(i,a),d] = vm>0 ? r - sc_emb(i,a,d) : 0
//           (diagonal removal == self-term subtraction; d2(i,i)=0 in mask)
__global__ __launch_bounds__(128) void k_msg(
        const float* __restrict__ S,
        const float4* __restrict__ meta4,
        const float2* __restrict__ rtm,
        const float* __restrict__ re,
        const float* __restrict__ tbl,
        const float* __restrict__ ae,
        float* __restrict__ out)
{
    int bi = blockIdx.x;
    int b  = bi >> 7;      // L = 128
    int i  = bi & 127;
    int t  = threadIdx.x;

    __shared__ float cx[128], cy[128], cz[128], cs[128], mm[128];
    __shared__ int   rts[128];
    __shared__ unsigned long long nbm[2];

    {
        int gj = (b << 7) + t;
        float4 m4 = meta4[gj];
        cx[t] = m4.x; cy[t] = m4.y; cz[t] = m4.z; cs[t] = m4.w;
        float2 rm = rtm[gj];
        mm[t] = rm.x; rts[t] = (int)rm.y;
    }
    __syncthreads();

    {
        // identical algebra to the reference: sq_i + sq_j - 2*dot
        float d2 = cs[i] + cs[t]
                 - 2.f * (cx[i] * cx[t] + cy[i] * cy[t] + cz[i] * cz[t]);
        unsigned long long bal = __ballot(d2 < RAD2);
        if ((t & 63) == 0) nbm[t >> 6] = bal;
    }
    __syncthreads();

    int d = t;
    const float* Sb = S + ((size_t)(b << 7)) * DIM + d;
    float r = 0.f;
    unsigned long long m0 = nbm[0], m1 = nbm[1];
    while (m0) {
        int j = __builtin_ctzll(m0); m0 &= m0 - 1;
        r += Sb[(size_t)j * DIM];
    }
    while (m1) {
        int j = 64 + __builtin_ctzll(m1); m1 &= m1 - 1;
        r += Sb[(size_t)j * DIM];
    }

    float m_i = mm[i];
    const float* trowi = tbl + rts[i] * NA37 + 3;
    float red = re[(size_t)bi * DIM + d];
    float* orow = out + (size_t)bi * NSC * DIM + d;
#pragma unroll
    for (int a = 0; a < NSC; ++a) {
        float vm = trowi[a] * m_i;
        float sc = vm * (red + vm * ae[(a + 3) * DIM + d]);
        orow[(size_t)a * DIM] = (vm > 0.f) ? (r - sc) : 0.f;
    }
}

extern "C" void kernel_launch(void* const* d_in, const int* in_sizes, int n_in,
                              void* d_out, int out_size, void* d_ws, size_t ws_size,
                              hipStream_t stream) {
    const float* aa   = (const float*)d_in[0];
    const float* re   = (const float*)d_in[1];
    const float* bb   = (const float*)d_in[2];
    const float* mask = (const float*)d_in[3];
    const float* tbl  = (const float*)d_in[4];
    const float* ae   = (const float*)d_in[5];
    float* out = (float*)d_out;

    const int BL = in_sizes[3];  // B*L = 256

    float*  Sws   = (float*)d_ws;                       // BL*128 floats
    float4* meta4 = (float4*)(Sws + (size_t)BL * DIM);  // BL float4
    float2* rtm   = (float2*)(meta4 + BL);              // BL float2

    k_pre<<<BL, DIM, 0, stream>>>(aa, re, bb, mask, tbl, ae, Sws, meta4, rtm);
    k_msg<<<BL, DIM, 0, stream>>>(Sws, meta4, rtm, re, tbl, ae, out);
}

// Round 5
// 13.407 us; speedup vs baseline: 1.1892x; 1.1892x over previous
//
#include <hip/hip_runtime.h>

#define NRES 23
#define NA37 37
#define NSC  34
#define DIM  128
#define RAD2 64.0f

// Single fused kernel, one dispatch (dispatch #2 measurably cost +1.4us).
// Block (b,i), 128 threads (one per embedding dim d).
//  phase 0: hoist ae[3..36][d] into 34 VGPRs (L1-hot, loaded once).
//  phase 1: thread t stages residue t's meta (CA*mask, |CA|^2, mask,
//           argmax restype) into LDS.
//  phase 2: thread t tests d2(i,t) -> __ballot -> 128-bit neighbor mask.
//  phase 3: for each set bit j (~2-6): s = sum_a vm*(re[j,d] + vm*ae_reg[a])
//           -- 34 FMAs from registers per neighbor.
//  phase 4: out[(i,a),d] = vm_i[a]>0 ? r - sc_emb(i,a,d) : 0
//           (diagonal removal == self-term subtraction; d2(i,i)=0 in mask).
__global__ __launch_bounds__(128) void k_fused(
        const float* __restrict__ aa,   // (BL,23)
        const float* __restrict__ re,   // (BL,128)
        const float* __restrict__ bb,   // (BL,4,3)
        const float* __restrict__ mask, // (BL,)
        const float* __restrict__ tbl,  // (23,37)
        const float* __restrict__ ae,   // (37,128)
        float* __restrict__ out)        // (BL,34,128)
{
    int bi = blockIdx.x;
    int b  = bi >> 7;      // L = 128
    int i  = bi & 127;
    int t  = threadIdx.x;

    __shared__ float cx[128], cy[128], cz[128], cs[128], mm[128];
    __shared__ int   rts[128];
    __shared__ unsigned long long nbm[2];

    int d = t;

    // ---- phase 0: hoist atom embeddings for this dim into registers ----
    float aer[NSC];
#pragma unroll
    for (int a = 0; a < NSC; ++a)
        aer[a] = ae[(a + 3) * DIM + d];

    // ---- phase 1: stage residue t of batch b ----
    {
        int gj = (b << 7) + t;
        float m = mask[gj];
        const float* bbr = bb + (size_t)gj * 12 + 3;   // atom 1 = CA
        float x = bbr[0] * m, y = bbr[1] * m, z = bbr[2] * m;
        cx[t] = x; cy[t] = y; cz[t] = z;
        cs[t] = x * x + y * y + z * z;
        mm[t] = m;

        // argmax over aa_pred[gj, 0:20]; cols 20..22 are -1e9 in the
        // reference and can never win against finite normals.
        const float* aarow = aa + (size_t)gj * NRES;
        int rt = 0; float best = aarow[0];
#pragma unroll
        for (int k = 1; k < 20; ++k) {
            float v = aarow[k];
            if (v > best) { best = v; rt = k; }
        }
        rts[t] = rt;
    }
    __syncthreads();

    // ---- phase 2: parallel adjacency ballot (thread t tests j = t) ----
    {
        // identical algebra to the reference: sq_i + sq_j - 2*dot
        float d2 = cs[i] + cs[t]
                 - 2.f * (cx[i] * cx[t] + cy[i] * cy[t] + cz[i] * cz[t]);
        unsigned long long bal = __ballot(d2 < RAD2);
        if ((t & 63) == 0) nbm[t >> 6] = bal;
    }
    __syncthreads();

    // ---- phase 3: accumulate over neighbors ----
    const float* reb = re + ((size_t)b << 7) * DIM + d;
    float r = 0.f;
    unsigned long long m0 = nbm[0], m1 = nbm[1];
    while (m0) {
        int j = __builtin_ctzll(m0); m0 &= m0 - 1;
        const float* trow = tbl + rts[j] * NA37 + 3;
        float mj  = mm[j];
        float rej = reb[(size_t)j * DIM];
        float s = 0.f;
#pragma unroll
        for (int a = 0; a < NSC; ++a) {
            float vm = trow[a] * mj;
            s += vm * (rej + vm * aer[a]);
        }
        r += s;
    }
    while (m1) {
        int j = 64 + __builtin_ctzll(m1); m1 &= m1 - 1;
        const float* trow = tbl + rts[j] * NA37 + 3;
        float mj  = mm[j];
        float rej = reb[(size_t)j * DIM];
        float s = 0.f;
#pragma unroll
        for (int a = 0; a < NSC; ++a) {
            float vm = trow[a] * mj;
            s += vm * (rej + vm * aer[a]);
        }
        r += s;
    }

    // ---- phase 4: epilogue ----
    float m_i = mm[i];
    const float* trowi = tbl + rts[i] * NA37 + 3;
    float red = reb[(size_t)i * DIM];
    float* orow = out + (size_t)bi * NSC * DIM + d;
#pragma unroll
    for (int a = 0; a < NSC; ++a) {
        float vm = trowi[a] * m_i;
        float sc = vm * (red + vm * aer[a]);
        orow[(size_t)a * DIM] = (vm > 0.f) ? (r - sc) : 0.f;
    }
}

extern "C" void kernel_launch(void* const* d_in, const int* in_sizes, int n_in,
                              void* d_out, int out_size, void* d_ws, size_t ws_size,
                              hipStream_t stream) {
    const float* aa   = (const float*)d_in[0];
    const float* re   = (const float*)d_in[1];
    const float* bb   = (const float*)d_in[2];
    const float* mask = (const float*)d_in[3];
    const float* tbl  = (const float*)d_in[4];
    const float* ae   = (const float*)d_in[5];
    float* out = (float*)d_out;

    const int BL = in_sizes[3];  // B*L = 256

    k_fused<<<BL, DIM, 0, stream>>>(aa, re, bb, mask, tbl, ae, out);
}

// Round 6
// 13.302 us; speedup vs baseline: 1.1986x; 1.0079x over previous
//
#include <hip/hip_runtime.h>

#define NRES 23
#define NA37 37
#define NSC  34
#define DIM  128
#define RAD2 64.0f

// Single fused kernel, one dispatch, ONE barrier.
// Block (b,i), 128 threads (one per embedding dim d).
//  phase 0: issue ae[3..36][d] loads into 34 VGPRs (overlaps phase 1).
//  phase 1: thread t stages residue t's meta (CA*mask, |CA|^2, mask,
//           argmax restype) into LDS.  __syncthreads().
//  phase 2: DUAL ballot — each thread tests j=lane and j=lane+64, so each
//           wave gets the full 128-bit neighbor mask in registers (no LDS
//           round-trip, no second barrier).
//  phase 3: for each set bit j (~2-6): s = sum_a vm*(re[j,d] + vm*ae_reg[a]).
//  phase 4: out[(i,a),d] = vm_i[a]>0 ? r - sc_emb(i,a,d) : 0
//           (diagonal removal == self-term subtraction; d2(i,i)=0 in mask).
__global__ __launch_bounds__(128) void k_fused(
        const float* __restrict__ aa,   // (BL,23)
        const float* __restrict__ re,   // (BL,128)
        const float* __restrict__ bb,   // (BL,4,3)
        const float* __restrict__ mask, // (BL,)
        const float* __restrict__ tbl,  // (23,37)
        const float* __restrict__ ae,   // (37,128)
        float* __restrict__ out)        // (BL,34,128)
{
    int bi = blockIdx.x;
    int b  = bi >> 7;      // L = 128
    int i  = bi & 127;
    int t  = threadIdx.x;
    int d  = t;

    __shared__ float cx[128], cy[128], cz[128], cs[128], mm[128];
    __shared__ int   rts[128];

    // ---- phase 0: hoist atom embeddings for this dim into registers ----
    float aer[NSC];
#pragma unroll
    for (int a = 0; a < NSC; ++a)
        aer[a] = ae[(a + 3) * DIM + d];

    // ---- phase 1: stage residue t of batch b ----
    {
        int gj = (b << 7) + t;
        float m = mask[gj];
        const float* bbr = bb + (size_t)gj * 12 + 3;   // atom 1 = CA
        float x = bbr[0] * m, y = bbr[1] * m, z = bbr[2] * m;
        cx[t] = x; cy[t] = y; cz[t] = z;
        cs[t] = x * x + y * y + z * z;
        mm[t] = m;

        // argmax over aa_pred[gj, 0:20]; cols 20..22 are -1e9 in the
        // reference and can never win against finite normals.
        const float* aarow = aa + (size_t)gj * NRES;
        int rt = 0; float best = aarow[0];
#pragma unroll
        for (int k = 1; k < 20; ++k) {
            float v = aarow[k];
            if (v > best) { best = v; rt = k; }
        }
        rts[t] = rt;
    }
    __syncthreads();

    // ---- phase 2: dual ballot (each wave builds the full 128-bit mask) ----
    unsigned long long m0, m1;
    {
        int lane = t & 63;
        float xi = cx[i], yi = cy[i], zi = cz[i], si = cs[i];
        // identical algebra to the reference: sq_i + sq_j - 2*dot
        float d2a = si + cs[lane]
                  - 2.f * (xi * cx[lane] + yi * cy[lane] + zi * cz[lane]);
        float d2b = si + cs[lane + 64]
                  - 2.f * (xi * cx[lane + 64] + yi * cy[lane + 64]
                           + zi * cz[lane + 64]);
        m0 = __ballot(d2a < RAD2);   // neighbors j = 0..63
        m1 = __ballot(d2b < RAD2);   // neighbors j = 64..127
    }

    // ---- phase 3: accumulate over neighbors ----
    const float* reb = re + ((size_t)b << 7) * DIM + d;
    float r = 0.f;
    while (m0) {
        int j = __builtin_ctzll(m0); m0 &= m0 - 1;
        const float* trow = tbl + rts[j] * NA37 + 3;
        float mj  = mm[j];
        float rej = reb[(size_t)j * DIM];
        float s = 0.f;
#pragma unroll
        for (int a = 0; a < NSC; ++a) {
            float vm = trow[a] * mj;
            s += vm * (rej + vm * aer[a]);
        }
        r += s;
    }
    while (m1) {
        int j = 64 + __builtin_ctzll(m1); m1 &= m1 - 1;
        const float* trow = tbl + rts[j] * NA37 + 3;
        float mj  = mm[j];
        float rej = reb[(size_t)j * DIM];
        float s = 0.f;
#pragma unroll
        for (int a = 0; a < NSC; ++a) {
            float vm = trow[a] * mj;
            s += vm * (rej + vm * aer[a]);
        }
        r += s;
    }

    // ---- phase 4: epilogue ----
    float m_i = mm[i];
    const float* trowi = tbl + rts[i] * NA37 + 3;
    float red = reb[(size_t)i * DIM];
    float* orow = out + (size_t)bi * NSC * DIM + d;
#pragma unroll
    for (int a = 0; a < NSC; ++a) {
        float vm = trowi[a] * m_i;
        float sc = vm * (red + vm * aer[a]);
        orow[(size_t)a * DIM] = (vm > 0.f) ? (r - sc) : 0.f;
    }
}

extern "C" void kernel_launch(void* const* d_in, const int* in_sizes, int n_in,
                              void* d_out, int out_size, void* d_ws, size_t ws_size,
                              hipStream_t stream) {
    const float* aa   = (const float*)d_in[0];
    const float* re   = (const float*)d_in[1];
    const float* bb   = (const float*)d_in[2];
    const float* mask = (const float*)d_in[3];
    const float* tbl  = (const float*)d_in[4];
    const float* ae   = (const float*)d_in[5];
    float* out = (float*)d_out;

    const int BL = in_sizes[3];  // B*L = 256

    k_fused<<<BL, DIM, 0, stream>>>(aa, re, bb, mask, tbl, ae, out);
}